// Round 6
// baseline (1314.239 us; speedup 1.0000x reference)
//
#include <hip/hip_runtime.h>
#include <stdint.h>

// Problem constants
#define B_  4096
#define D_  1024
#define R_  2048
#define MAXD 2560

typedef _Float16 half4v __attribute__((ext_vector_type(4)));
typedef _Float16 half8v __attribute__((ext_vector_type(8)));
typedef float    f32x4  __attribute__((ext_vector_type(4)));
typedef float    f32x16 __attribute__((ext_vector_type(16)));

// ---- workspace plane offsets (in halves) ----
constexpr size_t NX = (size_t)B_ * D_;        // X     4194304
constexpr size_t NP = (size_t)B_ * MAXD;      // P    10485760
constexpr size_t NI = (size_t)R_ * D_;        // Win   2097152
constexpr size_t NR = (size_t)R_ * R_;        // Wres  4194304
constexpr size_t NG = (size_t)3 * R_ * D_;    // Wg    6291456
constexpr size_t OXH = 0,         OXL = OXH + NX;
constexpr size_t OPH = OXL + NX,  OPL = OPH + NP;
constexpr size_t OIH = OPL + NP,  OIL = OIH + NI;
constexpr size_t ORH = OIL + NI,  ORL = ORH + NR;
constexpr size_t OGH = ORL + NR,  OGL = OGH + NG;
constexpr size_t WS_HALVES = OGL + NG;        // ~109 MB

__device__ inline void split4(const f32x4 v, half4v& h, half4v& l) {
    #pragma unroll
    for (int j = 0; j < 4; ++j) {
        h[j] = (_Float16)v[j];
        l[j] = (_Float16)(v[j] - (float)h[j]);
    }
}
__device__ inline float sigmoidf_(float x) { return 1.0f / (1.0f + expf(-x)); }

// global(per-lane gather, 16B) -> LDS(wave-uniform base + lane*16) DMA
__device__ inline void gld16(const _Float16* g, _Float16* s) {
    __builtin_amdgcn_global_load_lds(
        (const __attribute__((address_space(1))) void*)g,
        (__attribute__((address_space(3))) void*)(uintptr_t)s,
        16, 0, 0);
}

// ---- prep: elementwise fp32 -> fp16 hi/lo planes (row-major preserved) ----
__global__ __launch_bounds__(256)
void split_planes(const float* __restrict__ X, const float* __restrict__ P,
                  const float* __restrict__ Win, const float* __restrict__ Wres,
                  const float* __restrict__ Wg, _Float16* __restrict__ ws)
{
    size_t i = (size_t)blockIdx.x * 256 + threadIdx.x;   // one f32x4 per thread
    const float* src; _Float16 *hB, *lB; size_t base;
    if      (i < 1048576) { src = X;    hB = ws + OXH; lB = ws + OXL; base = 0; }
    else if (i < 3670016) { src = P;    hB = ws + OPH; lB = ws + OPL; base = 1048576; }
    else if (i < 4194304) { src = Win;  hB = ws + OIH; lB = ws + OIL; base = 3670016; }
    else if (i < 5242880) { src = Wres; hB = ws + ORH; lB = ws + ORL; base = 4194304; }
    else                  { src = Wg;   hB = ws + OGH; lB = ws + OGL; base = 5242880; }
    size_t j = i - base;
    f32x4 v = *((const f32x4*)src + j);
    half4v h, l; split4(v, h, l);
    *((half4v*)hB + j) = h;
    *((half4v*)lB + j) = l;
}

// ---- main fused kernel, DMA staging from pre-split planes ----
// pre = X*Win^T + prev*Wres^T (K=3072), gates = X*Wg^T (K=1024, 3 sets),
// state = o*( 0.9*f*prev + 0.1*tanh(i*pre) ), spike-subtract, fp32 store.
__global__ __launch_bounds__(256, 3)
void reservoir_mfma(const _Float16* __restrict__ ws,
                    const float* __restrict__ P,      // fp32 prev for epilogue
                    float* __restrict__ out)
{
    __shared__ _Float16 sA[2][4096];       // [plane][(rb*2+kb)*512 + lane*8]
    __shared__ _Float16 sW[2][4][2048];    // [plane][set][(nb*2+kb)*512 + lane*8]

    const int tid  = threadIdx.x;
    const int lane = tid & 63;
    const int wv   = tid >> 6;
    const int wm   = wv >> 1;              // rows wm*64..+64
    const int wn   = wv & 1;               // cols wn*32..+32
    const int m0   = blockIdx.y * 128;
    const int n0   = blockIdx.x * 64;

    f32x16 acc[4][2];
    #pragma unroll
    for (int s = 0; s < 4; ++s)
        #pragma unroll
        for (int mb = 0; mb < 2; ++mb)
            #pragma unroll
            for (int r = 0; r < 16; ++r) acc[s][mb][r] = 0.0f;

    const int arow = lane & 31;            // row-within-32 this lane gathers
    const int acol = (lane >> 5) * 8;      // k-offset this lane gathers

    for (int k0 = 0; k0 < D_ + R_; k0 += 32) {
        const bool ph1 = (k0 < D_);
        const size_t oAh = ph1 ? OXH : OPH;
        const size_t oAl = ph1 ? OXL : OPL;
        const int    ldA = ph1 ? D_ : MAXD;
        const int    kc  = ph1 ? k0 : k0 - D_;

        // ---- A tile: 16 regions (rb:4, kb:2, plane:2), 4 per wave ----
        #pragma unroll
        for (int i = 0; i < 4; ++i) {
            int a = i * 4 + wv;
            int rb = a >> 2, kb = (a >> 1) & 1, p = a & 1;
            const _Float16* g = ws + (p ? oAl : oAh)
                + (size_t)(m0 + rb * 32 + arow) * ldA + kc + kb * 16 + acol;
            gld16(g, &sA[p][(rb * 2 + kb) * 512]);
        }
        // ---- W tiles ----
        if (ph1) {   // 32 regions (set:4, nb:2, kb:2, plane:2), 8 per wave
            #pragma unroll
            for (int i = 0; i < 8; ++i) {
                int w = i * 4 + wv;
                int s = w >> 3, nb = (w >> 2) & 1, kb = (w >> 1) & 1, p = w & 1;
                size_t oh, ol; int row;
                if (s == 0) { oh = OIH; ol = OIL; row = n0 + nb * 32 + arow; }
                else        { oh = OGH; ol = OGL; row = (s - 1) * R_ + n0 + nb * 32 + arow; }
                const _Float16* g = ws + (p ? ol : oh)
                    + (size_t)row * D_ + k0 + kb * 16 + acol;
                gld16(g, &sW[p][s][(nb * 2 + kb) * 512]);
            }
        } else {     // set 0 only: 8 regions, 2 per wave
            #pragma unroll
            for (int i = 0; i < 2; ++i) {
                int w = i * 4 + wv;
                int nb = (w >> 2) & 1, kb = (w >> 1) & 1, p = w & 1;
                const _Float16* g = ws + (p ? ORL : ORH)
                    + (size_t)(n0 + nb * 32 + arow) * R_ + kc + kb * 16 + acol;
                gld16(g, &sW[p][0][(nb * 2 + kb) * 512]);
            }
        }
        __syncthreads();

        // ---- MFMA: two 32x32x16 k-steps, 3-way hi/lo split ----
        #pragma unroll
        for (int ks = 0; ks < 2; ++ks) {
            half8v ah0 = *(const half8v*)(&sA[0][((wm * 2 + 0) * 2 + ks) * 512 + lane * 8]);
            half8v al0 = *(const half8v*)(&sA[1][((wm * 2 + 0) * 2 + ks) * 512 + lane * 8]);
            half8v ah1 = *(const half8v*)(&sA[0][((wm * 2 + 1) * 2 + ks) * 512 + lane * 8]);
            half8v al1 = *(const half8v*)(&sA[1][((wm * 2 + 1) * 2 + ks) * 512 + lane * 8]);
            #pragma unroll
            for (int s = 0; s < 4; ++s) {
                if (!ph1 && s > 0) continue;
                half8v bh = *(const half8v*)(&sW[0][s][(wn * 2 + ks) * 512 + lane * 8]);
                half8v bl = *(const half8v*)(&sW[1][s][(wn * 2 + ks) * 512 + lane * 8]);
                acc[s][0] = __builtin_amdgcn_mfma_f32_32x32x16_f16(ah0, bh, acc[s][0], 0, 0, 0);
                acc[s][0] = __builtin_amdgcn_mfma_f32_32x32x16_f16(al0, bh, acc[s][0], 0, 0, 0);
                acc[s][0] = __builtin_amdgcn_mfma_f32_32x32x16_f16(ah0, bl, acc[s][0], 0, 0, 0);
                acc[s][1] = __builtin_amdgcn_mfma_f32_32x32x16_f16(ah1, bh, acc[s][1], 0, 0, 0);
                acc[s][1] = __builtin_amdgcn_mfma_f32_32x32x16_f16(al1, bh, acc[s][1], 0, 0, 0);
                acc[s][1] = __builtin_amdgcn_mfma_f32_32x32x16_f16(ah1, bl, acc[s][1], 0, 0, 0);
            }
        }
        __syncthreads();
    }

    // ---- epilogue: 32x32 C/D layout col=lane&31, row=(reg&3)+8*(reg>>2)+4*(lane>>5) ----
    const int col = n0 + wn * 32 + (lane & 31);
    const int rbase = m0 + wm * 64 + 4 * (lane >> 5);
    #pragma unroll
    for (int mb = 0; mb < 2; ++mb)
        #pragma unroll
        for (int r = 0; r < 16; ++r) {
            int row = rbase + mb * 32 + (r & 3) + 8 * (r >> 2);
            float pre = acc[0][mb][r];
            float ig  = sigmoidf_(acc[1][mb][r]);
            float fg  = sigmoidf_(acc[2][mb][r]);
            float og  = sigmoidf_(acc[3][mb][r]);
            float pv  = P[(size_t)row * MAXD + col];
            float st  = 0.9f * (fg * pv) + 0.1f * tanhf(ig * pre);
            st *= og;
            if (st > 0.5f) st -= 0.5f;
            out[(size_t)row * MAXD + col] = st;
        }
}

// ---- fallback (R5, passes at ~464 us) used if ws_size is too small ----
__global__ __launch_bounds__(256, 2)
void reservoir_fused_fb(const float* __restrict__ X, const float* __restrict__ P,
                        const float* __restrict__ Win, const float* __restrict__ Wres,
                        const float* __restrict__ Wg, float* __restrict__ out)
{
    __shared__ _Float16 sAh[4096], sAl[4096];
    __shared__ _Float16 sWh[4][2048], sWl[4][2048];
    const int tid = threadIdx.x, lane = tid & 63, wv = tid >> 6;
    const int wm = wv >> 1, wn = wv & 1;
    const int m0 = blockIdx.y * 128, n0 = blockIdx.x * 64;
    f32x16 acc[4][2];
    #pragma unroll
    for (int s = 0; s < 4; ++s)
        #pragma unroll
        for (int mb = 0; mb < 2; ++mb)
            #pragma unroll
            for (int r = 0; r < 16; ++r) acc[s][mb][r] = 0.0f;
    for (int k0 = 0; k0 < D_ + R_; k0 += 32) {
        const bool ph1 = (k0 < D_);
        {
            const float* src; int ld, kc;
            if (ph1) { src = X; ld = D_; kc = k0; } else { src = P; ld = MAXD; kc = k0 - D_; }
            #pragma unroll
            for (int i = 0; i < 4; ++i) {
                int t = i * 256 + tid, r = t >> 3, sel = t & 7, kq = sel >> 1, h4 = sel & 1;
                f32x4 v = *(const f32x4*)(src + (size_t)(m0 + r) * ld + kc + kq * 8 + h4 * 4);
                half4v h, l; split4(v, h, l);
                int off = ((r >> 5) * 2 + (kq >> 1)) * 512 + ((((kq & 1) << 5) | (r & 31)) * 8) + h4 * 4;
                *(half4v*)(&sAh[off]) = h; *(half4v*)(&sAl[off]) = l;
            }
        }
        {
            const float* src; int ld, kc;
            if (ph1) { src = Win; ld = D_; kc = k0; } else { src = Wres; ld = R_; kc = k0 - D_; }
            #pragma unroll
            for (int i = 0; i < 2; ++i) {
                int t = i * 256 + tid, r = t >> 3, sel = t & 7, kq = sel >> 1, h4 = sel & 1;
                f32x4 v = *(const f32x4*)(src + (size_t)(n0 + r) * ld + kc + kq * 8 + h4 * 4);
                half4v h, l; split4(v, h, l);
                int off = ((r >> 5) * 2 + (kq >> 1)) * 512 + ((((kq & 1) << 5) | (r & 31)) * 8) + h4 * 4;
                *(half4v*)(&sWh[0][off]) = h; *(half4v*)(&sWl[0][off]) = l;
            }
        }
        if (ph1) {
            #pragma unroll
            for (int g = 0; g < 3; ++g)
                #pragma unroll
                for (int i = 0; i < 2; ++i) {
                    int t = i * 256 + tid, r = t >> 3, sel = t & 7, kq = sel >> 1, h4 = sel & 1;
                    f32x4 v = *(const f32x4*)(Wg + (size_t)(g * R_ + n0 + r) * D_ + k0 + kq * 8 + h4 * 4);
                    half4v h, l; split4(v, h, l);
                    int off = ((r >> 5) * 2 + (kq >> 1)) * 512 + ((((kq & 1) << 5) | (r & 31)) * 8) + h4 * 4;
                    *(half4v*)(&sWh[1 + g][off]) = h; *(half4v*)(&sWl[1 + g][off]) = l;
                }
        }
        __syncthreads();
        #pragma unroll
        for (int ks = 0; ks < 2; ++ks) {
            half8v ah0 = *(const half8v*)(&sAh[((wm * 2 + 0) * 2 + ks) * 512 + lane * 8]);
            half8v al0 = *(const half8v*)(&sAl[((wm * 2 + 0) * 2 + ks) * 512 + lane * 8]);
            half8v ah1 = *(const half8v*)(&sAh[((wm * 2 + 1) * 2 + ks) * 512 + lane * 8]);
            half8v al1 = *(const half8v*)(&sAl[((wm * 2 + 1) * 2 + ks) * 512 + lane * 8]);
            #pragma unroll
            for (int s = 0; s < 4; ++s) {
                if (!ph1 && s > 0) continue;
                half8v bh = *(const half8v*)(&sWh[s][(wn * 2 + ks) * 512 + lane * 8]);
                half8v bl = *(const half8v*)(&sWl[s][(wn * 2 + ks) * 512 + lane * 8]);
                acc[s][0] = __builtin_amdgcn_mfma_f32_32x32x16_f16(ah0, bh, acc[s][0], 0, 0, 0);
                acc[s][0] = __builtin_amdgcn_mfma_f32_32x32x16_f16(al0, bh, acc[s][0], 0, 0, 0);
                acc[s][0] = __builtin_amdgcn_mfma_f32_32x32x16_f16(ah0, bl, acc[s][0], 0, 0, 0);
                acc[s][1] = __builtin_amdgcn_mfma_f32_32x32x16_f16(ah1, bh, acc[s][1], 0, 0, 0);
                acc[s][1] = __builtin_amdgcn_mfma_f32_32x32x16_f16(al1, bh, acc[s][1], 0, 0, 0);
                acc[s][1] = __builtin_amdgcn_mfma_f32_32x32x16_f16(ah1, bl, acc[s][1], 0, 0, 0);
            }
        }
        __syncthreads();
    }
    const int col = n0 + wn * 32 + (lane & 31);
    const int rbase = m0 + wm * 64 + 4 * (lane >> 5);
    #pragma unroll
    for (int mb = 0; mb < 2; ++mb)
        #pragma unroll
        for (int r = 0; r < 16; ++r) {
            int row = rbase + mb * 32 + (r & 3) + 8 * (r >> 2);
            float pre = acc[0][mb][r];
            float ig = sigmoidf_(acc[1][mb][r]);
            float fg = sigmoidf_(acc[2][mb][r]);
            float og = sigmoidf_(acc[3][mb][r]);
            float pv = P[(size_t)row * MAXD + col];
            float st = 0.9f * (fg * pv) + 0.1f * tanhf(ig * pre);
            st *= og;
            if (st > 0.5f) st -= 0.5f;
            out[(size_t)row * MAXD + col] = st;
        }
}

// Zero the pad region out[:, 2048:2560].
__global__ void pad_zero(float* __restrict__ out) {
    int idx = blockIdx.x * 256 + threadIdx.x;
    int row = idx >> 7;
    int c   = (idx & 127) * 4;
    *(f32x4*)(&out[(size_t)row * MAXD + R_ + c]) = (f32x4){0.f, 0.f, 0.f, 0.f};
}

extern "C" void kernel_launch(void* const* d_in, const int* in_sizes, int n_in,
                              void* d_out, int out_size, void* d_ws, size_t ws_size,
                              hipStream_t stream) {
    const float* X    = (const float*)d_in[0];
    const float* P    = (const float*)d_in[1];
    const float* Win  = (const float*)d_in[2];
    const float* Wres = (const float*)d_in[3];
    const float* Wg   = (const float*)d_in[4];
    float* out        = (float*)d_out;

    pad_zero<<<2048, 256, 0, stream>>>(out);

    if (ws_size >= WS_HALVES * sizeof(_Float16)) {
        _Float16* ws = (_Float16*)d_ws;
        split_planes<<<26624, 256, 0, stream>>>(X, P, Win, Wres, Wg, ws);
        dim3 grid(R_ / 64, B_ / 128);   // (32, 32)
        reservoir_mfma<<<grid, 256, 0, stream>>>(ws, P, out);
    } else {
        dim3 grid(R_ / 64, B_ / 128);
        reservoir_fused_fb<<<grid, 256, 0, stream>>>(X, P, Win, Wres, Wg, out);
    }
}

// Round 7
// 1242.671 us; speedup vs baseline: 1.0576x; 1.0576x over previous
//
#include <hip/hip_runtime.h>
#include <stdint.h>

// Problem constants
#define B_  4096
#define D_  1024
#define R_  2048
#define MAXD 2560

typedef _Float16 half4v __attribute__((ext_vector_type(4)));
typedef _Float16 half8v __attribute__((ext_vector_type(8)));
typedef float    f32x4  __attribute__((ext_vector_type(4)));
typedef float    f32x16 __attribute__((ext_vector_type(16)));

// ---- packed workspace (halves). Fragment-major regions of 512 halves (1024 B):
// region content: half[lane*8+j] = Elem[row = lane&31][k16 = (lane>>5)*8 + j]
// A-type (row blocks of 128): region id = ((mb*KC + kc)*4 + rb)*4 + kb*2 + plane
// W-type (row blocks of 64):  region id = ((nb*KC + kc)*2 + nb32)*4 + kb*2 + plane
constexpr size_t OX = 0;                         // X    packed: 32*32*16*512
constexpr size_t OP = 8388608;                   // P[:, :2048]: 32*64*16*512
constexpr size_t OI = 25165824;                  // Win: 32*32*8*512
constexpr size_t OR = 29360128;                  // Wres: 32*64*8*512
constexpr size_t OG = 37748736;                  // Wg:  96*32*8*512
constexpr size_t WS_HALVES = 50331648;           // 96 MB

__device__ inline float sigmoidf_(float x) { return 1.0f / (1.0f + expf(-x)); }

// global(lane-contiguous 16B) -> LDS(wave-uniform base + lane*16) DMA
__device__ inline void gld16(const _Float16* g, _Float16* s) {
    __builtin_amdgcn_global_load_lds(
        (const __attribute__((address_space(1))) void*)g,
        (__attribute__((address_space(3))) void*)(uintptr_t)s,
        16, 0, 0);
}

// ---- prep: fp32 -> fp16 hi/lo planes, packed fragment-major, LDS-transposed ----
// One wg = one (32 rows x 128 k) slab of one source matrix.
__global__ __launch_bounds__(256)
void pack_planes(const float* __restrict__ X, const float* __restrict__ P,
                 const float* __restrict__ Win, const float* __restrict__ Wres,
                 const float* __restrict__ Wg, _Float16* __restrict__ ws)
{
    __shared__ float ls[32 * 132];
    const int t = threadIdx.x;
    int id = blockIdx.x;
    const float* src; int ld; size_t obase; int KC; int sr, sk; bool atype;
    if (id < 1024)      { src = X;    ld = D_;   obase = OX; KC = 32; atype = true;  sr = id >> 3; sk = id & 7;  }
    else if (id < 3072) { id -= 1024; src = P;   ld = MAXD; obase = OP; KC = 64; atype = true;  sr = id >> 4; sk = id & 15; }
    else if (id < 3584) { id -= 3072; src = Win; ld = D_;   obase = OI; KC = 32; atype = false; sr = id >> 3; sk = id & 7;  }
    else if (id < 4608) { id -= 3584; src = Wres;ld = R_;   obase = OR; KC = 64; atype = false; sr = id >> 4; sk = id & 15; }
    else                { id -= 4608; src = Wg;  ld = D_;   obase = OG; KC = 32; atype = false; sr = id >> 3; sk = id & 7;  }
    const int r0 = sr * 32, k0 = sk * 128;

    // step 1: coalesced fp32 load -> LDS
    #pragma unroll
    for (int i = 0; i < 4; ++i) {
        int idx = i * 256 + t;
        int r = idx >> 5, kq = (idx & 31) * 4;
        f32x4 v = *(const f32x4*)(src + (size_t)(r0 + r) * ld + k0 + kq);
        *(f32x4*)(&ls[r * 132 + kq]) = v;
    }
    __syncthreads();

    // step 2: dest-major: 1024 chunks of 16 B (region: 16 = kcl2*kb2*plane... x 64 lanes)
    #pragma unroll
    for (int i = 0; i < 4; ++i) {
        int c = i * 256 + t;
        int reg = c >> 6, lane = c & 63;
        int k16 = reg >> 1, plane = reg & 1;      // k16 = kcl*2 + kb
        int kcl = k16 >> 1, kb = k16 & 1;
        int r = lane & 31, kh = lane >> 5;
        const float* p = &ls[r * 132 + kcl * 32 + kb * 16 + kh * 8];
        half8v o;
        #pragma unroll
        for (int j = 0; j < 8; ++j) {
            float v = p[j];
            _Float16 h = (_Float16)v;
            o[j] = plane ? (_Float16)(v - (float)h) : h;
        }
        int kc = sk * 4 + kcl;
        size_t region;
        if (atype) { int mb = sr >> 2, rb = sr & 3;
                     region = (((size_t)mb * KC + kc) * 4 + rb) * 4 + kb * 2 + plane; }
        else       { int nb = sr >> 1, nb32 = sr & 1;
                     region = (((size_t)nb * KC + kc) * 2 + nb32) * 4 + kb * 2 + plane; }
        *(half8v*)(ws + obase + region * 512 + lane * 8) = o;
    }
}

// ---- main fused kernel: coalesced DMA staging from packed planes ----
__global__ __launch_bounds__(256, 3)
void reservoir_mfma(const _Float16* __restrict__ ws,
                    const float* __restrict__ P,      // fp32 prev for epilogue
                    float* __restrict__ out)
{
    __shared__ _Float16 sA[2][4096];       // [plane][(rb*2+kb)*512 + lane*8]
    __shared__ _Float16 sW[2][4][2048];    // [plane][set][(nb*2+kb)*512 + lane*8]

    const int tid  = threadIdx.x;
    const int lane = tid & 63;
    const int wv   = tid >> 6;
    const int wm   = wv >> 1;              // rows wm*64..+64
    const int wn   = wv & 1;               // cols wn*32..+32

    // XCD swizzle: xcd = g&7 gets 8 n-blocks x 16 m-blocks (L2 reuse A:8x, W:16x)
    const int g  = blockIdx.x;
    const int x  = g & 7, q = g >> 3;
    const int bx = (x & 3) * 8 + (q & 7);   // n-block 0..31
    const int by = (x >> 2) * 16 + (q >> 3);// m-block 0..31
    const int m0 = by * 128, n0 = bx * 64;
    const int mb = by, n64 = bx;

    f32x16 acc[4][2];
    #pragma unroll
    for (int s = 0; s < 4; ++s)
        #pragma unroll
        for (int mt = 0; mt < 2; ++mt)
            #pragma unroll
            for (int r = 0; r < 16; ++r) acc[s][mt][r] = 0.0f;

    for (int k0 = 0; k0 < D_ + R_; k0 += 32) {
        const bool ph1 = (k0 < D_);
        const int kc = ph1 ? (k0 >> 5) : ((k0 - D_) >> 5);

        // ---- A: 16 regions (rb4, kb2, plane2), 4 per wave; lane-contiguous 1 KiB each
        #pragma unroll
        for (int i = 0; i < 4; ++i) {
            int a = i * 4 + wv;
            int rb = a >> 2, kb = (a >> 1) & 1, p = a & 1;
            size_t region = ph1
                ? ((((size_t)mb * 32 + kc) * 4 + rb) * 4 + kb * 2 + p)
                : ((((size_t)mb * 64 + kc) * 4 + rb) * 4 + kb * 2 + p);
            const _Float16* gp = ws + (ph1 ? OX : OP) + region * 512 + lane * 8;
            gld16(gp, &sA[p][(rb * 2 + kb) * 512]);
        }
        // ---- W tiles ----
        if (ph1) {   // 32 regions (set4, nb2, kb2, plane2), 8 per wave
            #pragma unroll
            for (int i = 0; i < 8; ++i) {
                int w = i * 4 + wv;
                int s = w >> 3, nbb = (w >> 2) & 1, kb = (w >> 1) & 1, p = w & 1;
                size_t region; size_t ob;
                if (s == 0) { ob = OI; region = (((size_t)n64 * 32 + kc) * 2 + nbb) * 4 + kb * 2 + p; }
                else        { ob = OG; size_t nb = (size_t)(s - 1) * 32 + n64;
                              region = ((nb * 32 + kc) * 2 + nbb) * 4 + kb * 2 + p; }
                const _Float16* gp = ws + ob + region * 512 + lane * 8;
                gld16(gp, &sW[p][s][(nbb * 2 + kb) * 512]);
            }
        } else {     // set 0 only: 8 regions, 2 per wave
            #pragma unroll
            for (int i = 0; i < 2; ++i) {
                int w = i * 4 + wv;
                int nbb = (w >> 2) & 1, kb = (w >> 1) & 1, p = w & 1;
                size_t region = (((size_t)n64 * 64 + kc) * 2 + nbb) * 4 + kb * 2 + p;
                const _Float16* gp = ws + OR + region * 512 + lane * 8;
                gld16(gp, &sW[p][0][(nbb * 2 + kb) * 512]);
            }
        }
        __syncthreads();

        // ---- MFMA: two 32x32x16 k-steps, 3-way hi/lo split ----
        #pragma unroll
        for (int ks = 0; ks < 2; ++ks) {
            half8v ah0 = *(const half8v*)(&sA[0][((wm * 2 + 0) * 2 + ks) * 512 + lane * 8]);
            half8v al0 = *(const half8v*)(&sA[1][((wm * 2 + 0) * 2 + ks) * 512 + lane * 8]);
            half8v ah1 = *(const half8v*)(&sA[0][((wm * 2 + 1) * 2 + ks) * 512 + lane * 8]);
            half8v al1 = *(const half8v*)(&sA[1][((wm * 2 + 1) * 2 + ks) * 512 + lane * 8]);
            #pragma unroll
            for (int s = 0; s < 4; ++s) {
                if (!ph1 && s > 0) continue;
                half8v bh = *(const half8v*)(&sW[0][s][(wn * 2 + ks) * 512 + lane * 8]);
                half8v bl = *(const half8v*)(&sW[1][s][(wn * 2 + ks) * 512 + lane * 8]);
                acc[s][0] = __builtin_amdgcn_mfma_f32_32x32x16_f16(ah0, bh, acc[s][0], 0, 0, 0);
                acc[s][0] = __builtin_amdgcn_mfma_f32_32x32x16_f16(al0, bh, acc[s][0], 0, 0, 0);
                acc[s][0] = __builtin_amdgcn_mfma_f32_32x32x16_f16(ah0, bl, acc[s][0], 0, 0, 0);
                acc[s][1] = __builtin_amdgcn_mfma_f32_32x32x16_f16(ah1, bh, acc[s][1], 0, 0, 0);
                acc[s][1] = __builtin_amdgcn_mfma_f32_32x32x16_f16(al1, bh, acc[s][1], 0, 0, 0);
                acc[s][1] = __builtin_amdgcn_mfma_f32_32x32x16_f16(ah1, bl, acc[s][1], 0, 0, 0);
            }
        }
        __syncthreads();
    }

    // ---- epilogue: 32x32 C/D layout col=lane&31, row=(reg&3)+8*(reg>>2)+4*(lane>>5) ----
    const int col = n0 + wn * 32 + (lane & 31);
    const int rbase = m0 + wm * 64 + 4 * (lane >> 5);
    #pragma unroll
    for (int mt = 0; mt < 2; ++mt)
        #pragma unroll
        for (int r = 0; r < 16; ++r) {
            int row = rbase + mt * 32 + (r & 3) + 8 * (r >> 2);
            float pre = acc[0][mt][r];
            float ig  = sigmoidf_(acc[1][mt][r]);
            float fg  = sigmoidf_(acc[2][mt][r]);
            float og  = sigmoidf_(acc[3][mt][r]);
            float pv  = P[(size_t)row * MAXD + col];
            float st  = 0.9f * (fg * pv) + 0.1f * tanhf(ig * pre);
            st *= og;
            if (st > 0.5f) st -= 0.5f;
            out[(size_t)row * MAXD + col] = st;
        }
}

// ---- fallback (R5-style, ~530 us total) if ws too small ----
__device__ inline void split4(const f32x4 v, half4v& h, half4v& l) {
    #pragma unroll
    for (int j = 0; j < 4; ++j) { h[j] = (_Float16)v[j]; l[j] = (_Float16)(v[j] - (float)h[j]); }
}
__global__ __launch_bounds__(256, 2)
void reservoir_fused_fb(const float* __restrict__ X, const float* __restrict__ P,
                        const float* __restrict__ Win, const float* __restrict__ Wres,
                        const float* __restrict__ Wg, float* __restrict__ out)
{
    __shared__ _Float16 sAh[4096], sAl[4096];
    __shared__ _Float16 sWh[4][2048], sWl[4][2048];
    const int tid = threadIdx.x, lane = tid & 63, wv = tid >> 6;
    const int wm = wv >> 1, wn = wv & 1;
    const int m0 = blockIdx.y * 128, n0 = blockIdx.x * 64;
    f32x16 acc[4][2];
    #pragma unroll
    for (int s = 0; s < 4; ++s)
        #pragma unroll
        for (int mt = 0; mt < 2; ++mt)
            #pragma unroll
            for (int r = 0; r < 16; ++r) acc[s][mt][r] = 0.0f;
    for (int k0 = 0; k0 < D_ + R_; k0 += 32) {
        const bool ph1 = (k0 < D_);
        {
            const float* src; int ld, kc;
            if (ph1) { src = X; ld = D_; kc = k0; } else { src = P; ld = MAXD; kc = k0 - D_; }
            #pragma unroll
            for (int i = 0; i < 4; ++i) {
                int t = i * 256 + tid, r = t >> 3, sel = t & 7, kq = sel >> 1, h4 = sel & 1;
                f32x4 v = *(const f32x4*)(src + (size_t)(m0 + r) * ld + kc + kq * 8 + h4 * 4);
                half4v h, l; split4(v, h, l);
                int off = ((r >> 5) * 2 + (kq >> 1)) * 512 + ((((kq & 1) << 5) | (r & 31)) * 8) + h4 * 4;
                *(half4v*)(&sAh[off]) = h; *(half4v*)(&sAl[off]) = l;
            }
        }
        {
            const float* src; int ld, kc;
            if (ph1) { src = Win; ld = D_; kc = k0; } else { src = Wres; ld = R_; kc = k0 - D_; }
            #pragma unroll
            for (int i = 0; i < 2; ++i) {
                int t = i * 256 + tid, r = t >> 3, sel = t & 7, kq = sel >> 1, h4 = sel & 1;
                f32x4 v = *(const f32x4*)(src + (size_t)(n0 + r) * ld + kc + kq * 8 + h4 * 4);
                half4v h, l; split4(v, h, l);
                int off = ((r >> 5) * 2 + (kq >> 1)) * 512 + ((((kq & 1) << 5) | (r & 31)) * 8) + h4 * 4;
                *(half4v*)(&sWh[0][off]) = h; *(half4v*)(&sWl[0][off]) = l;
            }
        }
        if (ph1) {
            #pragma unroll
            for (int gg = 0; gg < 3; ++gg)
                #pragma unroll
                for (int i = 0; i < 2; ++i) {
                    int t = i * 256 + tid, r = t >> 3, sel = t & 7, kq = sel >> 1, h4 = sel & 1;
                    f32x4 v = *(const f32x4*)(Wg + (size_t)(gg * R_ + n0 + r) * D_ + k0 + kq * 8 + h4 * 4);
                    half4v h, l; split4(v, h, l);
                    int off = ((r >> 5) * 2 + (kq >> 1)) * 512 + ((((kq & 1) << 5) | (r & 31)) * 8) + h4 * 4;
                    *(half4v*)(&sWh[1 + gg][off]) = h; *(half4v*)(&sWl[1 + gg][off]) = l;
                }
        }
        __syncthreads();
        #pragma unroll
        for (int ks = 0; ks < 2; ++ks) {
            half8v ah0 = *(const half8v*)(&sAh[((wm * 2 + 0) * 2 + ks) * 512 + lane * 8]);
            half8v al0 = *(const half8v*)(&sAl[((wm * 2 + 0) * 2 + ks) * 512 + lane * 8]);
            half8v ah1 = *(const half8v*)(&sAh[((wm * 2 + 1) * 2 + ks) * 512 + lane * 8]);
            half8v al1 = *(const half8v*)(&sAl[((wm * 2 + 1) * 2 + ks) * 512 + lane * 8]);
            #pragma unroll
            for (int s = 0; s < 4; ++s) {
                if (!ph1 && s > 0) continue;
                half8v bh = *(const half8v*)(&sWh[s][(wn * 2 + ks) * 512 + lane * 8]);
                half8v bl = *(const half8v*)(&sWl[s][(wn * 2 + ks) * 512 + lane * 8]);
                acc[s][0] = __builtin_amdgcn_mfma_f32_32x32x16_f16(ah0, bh, acc[s][0], 0, 0, 0);
                acc[s][0] = __builtin_amdgcn_mfma_f32_32x32x16_f16(al0, bh, acc[s][0], 0, 0, 0);
                acc[s][0] = __builtin_amdgcn_mfma_f32_32x32x16_f16(ah0, bl, acc[s][0], 0, 0, 0);
                acc[s][1] = __builtin_amdgcn_mfma_f32_32x32x16_f16(ah1, bh, acc[s][1], 0, 0, 0);
                acc[s][1] = __builtin_amdgcn_mfma_f32_32x32x16_f16(al1, bh, acc[s][1], 0, 0, 0);
                acc[s][1] = __builtin_amdgcn_mfma_f32_32x32x16_f16(ah1, bl, acc[s][1], 0, 0, 0);
            }
        }
        __syncthreads();
    }
    const int col = n0 + wn * 32 + (lane & 31);
    const int rbase = m0 + wm * 64 + 4 * (lane >> 5);
    #pragma unroll
    for (int mt = 0; mt < 2; ++mt)
        #pragma unroll
        for (int r = 0; r < 16; ++r) {
            int row = rbase + mt * 32 + (r & 3) + 8 * (r >> 2);
            float pre = acc[0][mt][r];
            float ig = sigmoidf_(acc[1][mt][r]);
            float fg = sigmoidf_(acc[2][mt][r]);
            float og = sigmoidf_(acc[3][mt][r]);
            float pv = P[(size_t)row * MAXD + col];
            float st = 0.9f * (fg * pv) + 0.1f * tanhf(ig * pre);
            st *= og;
            if (st > 0.5f) st -= 0.5f;
            out[(size_t)row * MAXD + col] = st;
        }
}

// Zero the pad region out[:, 2048:2560].
__global__ void pad_zero(float* __restrict__ out) {
    int idx = blockIdx.x * 256 + threadIdx.x;
    int row = idx >> 7;
    int c   = (idx & 127) * 4;
    *(f32x4*)(&out[(size_t)row * MAXD + R_ + c]) = (f32x4){0.f, 0.f, 0.f, 0.f};
}

extern "C" void kernel_launch(void* const* d_in, const int* in_sizes, int n_in,
                              void* d_out, int out_size, void* d_ws, size_t ws_size,
                              hipStream_t stream) {
    const float* X    = (const float*)d_in[0];
    const float* P    = (const float*)d_in[1];
    const float* Win  = (const float*)d_in[2];
    const float* Wres = (const float*)d_in[3];
    const float* Wg   = (const float*)d_in[4];
    float* out        = (float*)d_out;

    pad_zero<<<2048, 256, 0, stream>>>(out);

    if (ws_size >= WS_HALVES * sizeof(_Float16)) {
        _Float16* ws = (_Float16*)d_ws;
        pack_planes<<<6144, 256, 0, stream>>>(X, P, Win, Wres, Wg, ws);
        reservoir_mfma<<<1024, 256, 0, stream>>>(ws, P, out);
    } else {
        dim3 grid(R_ / 64, B_ / 128);
        reservoir_fused_fb<<<grid, 256, 0, stream>>>(X, P, Win, Wres, Wg, out);
    }
}